// Round 7
// baseline (1241.687 us; speedup 1.0000x reference)
//
#include <hip/hip_runtime.h>
#include <math.h>

#define BB 2
#define TT 8192
#define HH 8
#define DD 64
#define NCC 128
#define MM 4
#define WW (TT/NCC)     // 64
#define T2 (2*TT)
#define SMAX 32         // slot cap per target row (cnt<=NC=128; overflow path below)
#define SK 68           // LDS row stride: 68*4=272 B = 16B-aligned -> ds_read_b128

// ---------------- Kernel A: normalize + cdist + aux(min d2) ----------------
// ROUND-2 VERBATIM — FROZEN. The top-64 boundary is fp-sensitive: changing the
// dot contraction (explicit fmaf interleave, s_load means) changed distance
// bits and flipped selections vs the reference (rounds 3-5 failures). Do NOT
// touch expression forms here.
__global__ __launch_bounds__(256) void kdist(
    const float* __restrict__ q, const float* __restrict__ k,
    const float* __restrict__ means,
    float* __restrict__ qd, float* __restrict__ kd, float* __restrict__ aux)
{
  __shared__ float sm[NCC * DD];
  __shared__ float sm2[NCC];
  __shared__ float red[4];
  const int b = blockIdx.z, h = blockIdx.y;
  const int tid = threadIdx.x;

  const float4* mp = (const float4*)(means + (size_t)h * NCC * DD);
  float4* smp = (float4*)sm;
  for (int i = tid; i < NCC * DD / 4; i += 256) smp[i] = mp[i];
  __syncthreads();
  if (tid < NCC) {
    float s = 0.f;
    #pragma unroll
    for (int d = 0; d < DD; ++d) { float v = sm[tid * DD + d]; s += v * v; }
    sm2[tid] = s;
  }
  __syncthreads();

  const int tp = blockIdx.x * 256 + tid;               // t' in [0,2T)
  const size_t bh = (size_t)(b * HH + h);
  const float* src = (tp < TT) ? (q + (bh * TT + tp) * DD)
                               : (k + (bh * TT + (tp - TT)) * DD);
  float x[DD];
  float ss = 0.f;
  #pragma unroll
  for (int i = 0; i < DD / 4; ++i) {
    float4 v = ((const float4*)src)[i];
    x[4*i] = v.x; x[4*i+1] = v.y; x[4*i+2] = v.z; x[4*i+3] = v.w;
    ss += v.x*v.x + v.y*v.y + v.z*v.z + v.w*v.w;
  }
  const float scale = 1.f / (sqrtf(ss) + 1e-6f);
  float x2 = 0.f;
  #pragma unroll
  for (int i = 0; i < DD; ++i) { x[i] *= scale; x2 += x[i] * x[i]; }

  float* dst = (tp < TT) ? (qd + (bh * NCC) * TT + tp)
                         : (kd + (bh * NCC) * TT + (tp - TT));
  float mind2 = 1e30f;
  for (int c = 0; c < NCC; ++c) {
    const float* mrow = sm + c * DD;
    float dot = 0.f;
    #pragma unroll
    for (int d = 0; d < DD; ++d) dot += x[d] * mrow[d];
    float d2 = fmaxf(x2 + sm2[c] - 2.f * dot, 0.f);
    mind2 = fminf(mind2, d2);
    dst[(size_t)c * TT] = sqrtf(d2);
  }

  float v = mind2;
  #pragma unroll
  for (int off = 32; off; off >>= 1) v += __shfl_down(v, off, 64);
  if ((tid & 63) == 0) red[tid >> 6] = v;
  __syncthreads();
  if (tid == 0) atomicAdd(aux, red[0] + red[1] + red[2] + red[3]);
}

// ---------------- Kernel B: top-64 smallest per row, one wave per row ----------------
// grid: (NC, H, 2B), block 64. Row lives in registers (128 vals/lane); tau by
// bitwise binary search with shfl_xor butterfly reductions — no barriers, no
// LDS in the hot loop. Same set semantics as the validated round-6 version
// (tau = 64th-smallest pattern, all <tau, lowest-index ties); register and
// LDS variants proven equivalent by rounds 4/5 identical outputs.
__global__ __launch_bounds__(64) void ktopk(
    const float* __restrict__ qd, const float* __restrict__ kd,
    int* __restrict__ idxq, int* __restrict__ idxk)
{
  __shared__ int outIdx[WW];
  __shared__ int pos;

  const int c = blockIdx.x, h = blockIdx.y;
  const int b = blockIdx.z >> 1, isK = blockIdx.z & 1;
  const int tid = threadIdx.x;                 // lane 0..63
  const size_t rowoff = ((size_t)(b * HH + h) * NCC + c) * TT;
  const float4* row4 = (const float4*)((isK ? kd : qd) + rowoff);

  unsigned int u[128];                         // value at index j*256 + tid*4 + m
  #pragma unroll
  for (int j = 0; j < 32; ++j) {
    float4 v = row4[j * 64 + tid];
    u[4*j+0] = __float_as_uint(v.x);
    u[4*j+1] = __float_as_uint(v.y);
    u[4*j+2] = __float_as_uint(v.z);
    u[4*j+3] = __float_as_uint(v.w);
  }
  if (tid == 0) pos = 0;
  __syncthreads();

  // bitwise binary search for the 64th-smallest bit pattern (bit31 sign = 0)
  unsigned int tau = 0u;
  for (int bit = 30; bit >= 0; --bit) {
    const unsigned int cand = tau | (1u << bit);
    int cnt = 0;
    #pragma unroll
    for (int i = 0; i < 128; ++i) cnt += (u[i] < cand) ? 1 : 0;
    #pragma unroll
    for (int off = 32; off; off >>= 1) cnt += __shfl_xor(cnt, off, 64);
    if (cnt < WW) tau = cand;                  // 64th smallest >= cand
  }
  int bcnt = 0;
  #pragma unroll
  for (int i = 0; i < 128; ++i) bcnt += (u[i] < tau) ? 1 : 0;
  #pragma unroll
  for (int off = 32; off; off >>= 1) bcnt += __shfl_xor(bcnt, off, 64);
  const int base = bcnt;                       // strictly-below count (<= 63)
  const int need = WW - base;

  // collect strictly-below
  #pragma unroll
  for (int i = 0; i < 128; ++i) {
    if (u[i] < tau) {
      int p = atomicAdd(&pos, 1);
      outIdx[p] = (i >> 2) * 256 + tid * 4 + (i & 3);
    }
  }
  __syncthreads();

  // lowest `need` indices with value == tau (need is usually 1)
  int last = -1;
  for (int e = 0; e < need; ++e) {
    int loc = 0x7fffffff;
    #pragma unroll
    for (int i = 0; i < 128; ++i) {
      const int idx = (i >> 2) * 256 + tid * 4 + (i & 3);
      if (u[i] == tau && idx > last && idx < loc) loc = idx;
    }
    #pragma unroll
    for (int off = 32; off; off >>= 1) loc = min(loc, __shfl_xor(loc, off, 64));
    if (tid == 0) outIdx[base + e] = loc;
    last = loc;                                // butterfly -> uniform across wave
  }
  __syncthreads();

  int* dstp = (isK ? idxk : idxq) + ((size_t)(b * HH + h) * NCC + c) * WW;
  dstp[tid] = outIdx[tid];
}

// ---------------- Kernel C: gather + attention -> dense per-cluster out ----------------
// grid: (NC, H, B), block 256. SK=68 -> 16B-aligned LDS rows, explicit float4
// LDS reads (ds_read_b128). No atomics; coalesced float4 stores.
__global__ __launch_bounds__(256) void kattn(
    const float* __restrict__ q, const float* __restrict__ kg,
    const float* __restrict__ vg, const float* __restrict__ memk,
    const float* __restrict__ memv, const int* __restrict__ idxq,
    const int* __restrict__ idxk, float* __restrict__ outc)
{
  __shared__ float Ks[(MM + WW) * SK];   // 68 x 68 floats = 18.5 KB
  __shared__ float Vs[(MM + WW) * SK];
  __shared__ int tq[WW];
  __shared__ int tk[WW];

  const int c = blockIdx.x, h = blockIdx.y, b = blockIdx.z;
  const int tid = threadIdx.x;
  const size_t bh = (size_t)(b * HH + h);

  if (tid < WW) tq[tid] = idxq[(bh * NCC + c) * WW + tid];
  else if (tid < 2 * WW) tk[tid - WW] = idxk[(bh * NCC + c) * WW + tid - WW];
  __syncthreads();

  const int r = tid >> 2, part = tid & 3;

  for (int j = r; j < MM + WW; j += 64) {
    const float* sk = (j < MM)
        ? memk + (((size_t)(h * NCC + c)) * MM + j) * DD + part * 16
        : kg + (bh * TT + tk[j - MM]) * DD + part * 16;
    const float* sv = (j < MM)
        ? memv + (((size_t)(h * NCC + c)) * MM + j) * DD + part * 16
        : vg + (bh * TT + tk[j - MM]) * DD + part * 16;
    #pragma unroll
    for (int i = 0; i < 4; ++i) {
      *(float4*)&Ks[j * SK + part * 16 + 4 * i] = ((const float4*)sk)[i];
      *(float4*)&Vs[j * SK + part * 16 + 4 * i] = ((const float4*)sv)[i];
    }
  }
  __syncthreads();

  // dots: thread (r, part) handles keys j in [part*17, part*17+17)
  float s[17];
  {
    float qr[DD];
    const float* qsrc = q + (bh * TT + tq[r]) * DD;
    #pragma unroll
    for (int i = 0; i < DD / 4; ++i) {
      float4 v = ((const float4*)qsrc)[i];
      qr[4*i] = v.x; qr[4*i+1] = v.y; qr[4*i+2] = v.z; qr[4*i+3] = v.w;
    }
    #pragma unroll
    for (int jj = 0; jj < 17; ++jj) {
      const float4* krow = (const float4*)&Ks[(part * 17 + jj) * SK];
      float a0 = 0.f, a1 = 0.f, a2 = 0.f, a3 = 0.f;
      #pragma unroll
      for (int i = 0; i < DD / 4; ++i) {
        float4 kv = krow[i];
        a0 = fmaf(qr[4*i+0], kv.x, a0);
        a1 = fmaf(qr[4*i+1], kv.y, a1);
        a2 = fmaf(qr[4*i+2], kv.z, a2);
        a3 = fmaf(qr[4*i+3], kv.w, a3);
      }
      s[jj] = ((a0 + a1) + (a2 + a3)) * 0.125f;
    }
  }
  float mx = s[0];
  #pragma unroll
  for (int jj = 1; jj < 17; ++jj) mx = fmaxf(mx, s[jj]);
  mx = fmaxf(mx, __shfl_xor(mx, 1, 64));
  mx = fmaxf(mx, __shfl_xor(mx, 2, 64));
  float sum = 0.f;
  #pragma unroll
  for (int jj = 0; jj < 17; ++jj) { s[jj] = expf(s[jj] - mx); sum += s[jj]; }
  sum += __shfl_xor(sum, 1, 64);
  sum += __shfl_xor(sum, 2, 64);
  const float inv = 1.f / sum;
  #pragma unroll
  for (int jj = 0; jj < 17; ++jj) s[jj] *= inv;

  // PV: each lane accumulates its 17 keys over all 64 d (float4 LDS reads),
  // then quad-reduce and write the lane's 16-wide slice.
  float4 acc[16];
  #pragma unroll
  for (int i = 0; i < 16; ++i) acc[i] = make_float4(0.f, 0.f, 0.f, 0.f);
  #pragma unroll
  for (int jj = 0; jj < 17; ++jj) {
    const float p = s[jj];
    const float4* vrow = (const float4*)&Vs[(part * 17 + jj) * SK];
    #pragma unroll
    for (int i = 0; i < 16; ++i) {
      float4 vv = vrow[i];
      acc[i].x = fmaf(p, vv.x, acc[i].x);
      acc[i].y = fmaf(p, vv.y, acc[i].y);
      acc[i].z = fmaf(p, vv.z, acc[i].z);
      acc[i].w = fmaf(p, vv.w, acc[i].w);
    }
  }
  #pragma unroll
  for (int i = 0; i < 16; ++i) {
    acc[i].x += __shfl_xor(acc[i].x, 1, 64); acc[i].x += __shfl_xor(acc[i].x, 2, 64);
    acc[i].y += __shfl_xor(acc[i].y, 1, 64); acc[i].y += __shfl_xor(acc[i].y, 2, 64);
    acc[i].z += __shfl_xor(acc[i].z, 1, 64); acc[i].z += __shfl_xor(acc[i].z, 2, 64);
    acc[i].w += __shfl_xor(acc[i].w, 1, 64); acc[i].w += __shfl_xor(acc[i].w, 2, 64);
  }
  float* obase = outc + (((bh * NCC + c) * WW) + r) * DD + part * 16;
  #pragma unroll
  for (int i = 0; i < 4; ++i)
    ((float4*)obase)[i] = acc[part * 4 + i];

}

// ---------------- Kernel C2: inverted index (one int atomic per selection) ----------------
__global__ __launch_bounds__(256) void kindex(
    const int* __restrict__ idxq, const float* __restrict__ outc,
    int* __restrict__ cnt, int* __restrict__ slots, float* __restrict__ out)
{
  const int i = blockIdx.x * 256 + threadIdx.x;       // over B*H*NC*W
  const int bh = i >> 13;                             // NC*W = 8192
  const int e = i & 8191;
  const int t = idxq[i];
  const int row = bh * TT + t;
  const int p = atomicAdd(&cnt[row], 1);
  if (p < SMAX) {
    slots[(size_t)row * SMAX + p] = e;
  } else {
    const float* src = outc + ((size_t)(bh * (NCC * WW)) + e) * DD;
    for (int d = 0; d < DD; ++d) atomicAdd(&out[(size_t)row * DD + d], src[d]);
  }
}

// ---------------- Kernel D: gather slots + divide + aux ----------------
__global__ __launch_bounds__(256) void kfinal(
    float* __restrict__ outp, const int* __restrict__ cnt,
    const int* __restrict__ slots, const float* __restrict__ outc,
    const float* __restrict__ aux)
{
  const size_t n = (size_t)BB * HH * TT * DD;
  const size_t i = (size_t)blockIdx.x * 256 + threadIdx.x;
  if (i < n) {
    const int row = (int)(i >> 6);
    const int d = (int)(i & 63);
    const int bh = row >> 13;
    const int c = cnt[row];
    const int m = c < SMAX ? c : SMAX;
    float sum = outp[i];
    for (int s = 0; s < m; ++s) {
      const int e = slots[(size_t)row * SMAX + s];
      sum += outc[((size_t)(bh * (NCC * WW)) + e) * DD + d];
    }
    outp[i] = sum / ((float)c + 1e-5f);
  }
  if (i == 0) outp[n] = aux[0] * (0.0001f / (float)((size_t)BB * HH * 2 * TT * DD));
}

extern "C" void kernel_launch(void* const* d_in, const int* in_sizes, int n_in,
                              void* d_out, int out_size, void* d_ws, size_t ws_size,
                              hipStream_t stream) {
  (void)in_sizes; (void)n_in; (void)out_size; (void)ws_size;
  const float* q     = (const float*)d_in[0];
  const float* k     = (const float*)d_in[1];
  const float* v     = (const float*)d_in[2];
  const float* means = (const float*)d_in[3];
  const float* memk  = (const float*)d_in[4];
  const float* memv  = (const float*)d_in[5];
  float* out = (float*)d_out;

  const size_t NQ   = (size_t)BB * HH * NCC * TT;   // 16,777,216
  const size_t NIDX = (size_t)BB * HH * NCC * WW;   // 131,072
  const size_t NROW = (size_t)BB * HH * TT;         // 131,072

  float* qd   = (float*)d_ws;
  float* kd   = qd + NQ;
  int*   idxq = (int*)(kd + NQ);
  int*   idxk = idxq + NIDX;
  int*   cnt  = idxk + NIDX;
  float* aux  = (float*)(cnt + NROW);
  float* outc  = qd;                                // dead after ktopk -> reuse
  int*   slots = (int*)kd;

  const size_t n = (size_t)BB * HH * TT * DD;
  hipMemsetAsync(out, 0, n * sizeof(float), stream);
  hipMemsetAsync(cnt, 0, (NROW + 1) * sizeof(int), stream);  // cnt + aux

  kdist<<<dim3(T2 / 256, HH, BB), 256, 0, stream>>>(q, k, means, qd, kd, aux);
  ktopk<<<dim3(NCC, HH, 2 * BB), 64, 0, stream>>>(qd, kd, idxq, idxk);
  kattn<<<dim3(NCC, HH, BB), 256, 0, stream>>>(q, k, v, memk, memv, idxq, idxk, outc);
  kindex<<<(int)(NIDX / 256), 256, 0, stream>>>(idxq, outc, cnt, slots, out);
  kfinal<<<(int)((n + 255) / 256), 256, 0, stream>>>(out, cnt, slots, outc, aux);
}

// Round 8
// 478.029 us; speedup vs baseline: 2.5975x; 2.5975x over previous
//
#include <hip/hip_runtime.h>
#include <math.h>

#define BB 2
#define TT 8192
#define HH 8
#define DD 64
#define NCC 128
#define MM 4
#define WW (TT/NCC)     // 64
#define T2 (2*TT)
#define SMAX 32         // slot cap per target row (cnt<=NC=128; overflow path below)
#define SK 65           // padded LDS row stride for attention tiles
#define TIEMAX 256

// ---------------- Kernel A: normalize + cdist + aux(min d2) ----------------
// ROUND-2 VERBATIM — FROZEN. The top-64 boundary is fp-sensitive: changing the
// dot contraction (explicit fmaf interleave, s_load means) changed distance
// bits and flipped selections vs the reference (rounds 3-5 failures). Do NOT
// touch expression forms here.
__global__ __launch_bounds__(256) void kdist(
    const float* __restrict__ q, const float* __restrict__ k,
    const float* __restrict__ means,
    float* __restrict__ qd, float* __restrict__ kd, float* __restrict__ aux)
{
  __shared__ float sm[NCC * DD];
  __shared__ float sm2[NCC];
  __shared__ float red[4];
  const int b = blockIdx.z, h = blockIdx.y;
  const int tid = threadIdx.x;

  const float4* mp = (const float4*)(means + (size_t)h * NCC * DD);
  float4* smp = (float4*)sm;
  for (int i = tid; i < NCC * DD / 4; i += 256) smp[i] = mp[i];
  __syncthreads();
  if (tid < NCC) {
    float s = 0.f;
    #pragma unroll
    for (int d = 0; d < DD; ++d) { float v = sm[tid * DD + d]; s += v * v; }
    sm2[tid] = s;
  }
  __syncthreads();

  const int tp = blockIdx.x * 256 + tid;               // t' in [0,2T)
  const size_t bh = (size_t)(b * HH + h);
  const float* src = (tp < TT) ? (q + (bh * TT + tp) * DD)
                               : (k + (bh * TT + (tp - TT)) * DD);
  float x[DD];
  float ss = 0.f;
  #pragma unroll
  for (int i = 0; i < DD / 4; ++i) {
    float4 v = ((const float4*)src)[i];
    x[4*i] = v.x; x[4*i+1] = v.y; x[4*i+2] = v.z; x[4*i+3] = v.w;
    ss += v.x*v.x + v.y*v.y + v.z*v.z + v.w*v.w;
  }
  const float scale = 1.f / (sqrtf(ss) + 1e-6f);
  float x2 = 0.f;
  #pragma unroll
  for (int i = 0; i < DD; ++i) { x[i] *= scale; x2 += x[i] * x[i]; }

  float* dst = (tp < TT) ? (qd + (bh * NCC) * TT + tp)
                         : (kd + (bh * NCC) * TT + (tp - TT));
  float mind2 = 1e30f;
  for (int c = 0; c < NCC; ++c) {
    const float* mrow = sm + c * DD;
    float dot = 0.f;
    #pragma unroll
    for (int d = 0; d < DD; ++d) dot += x[d] * mrow[d];
    float d2 = fmaxf(x2 + sm2[c] - 2.f * dot, 0.f);
    mind2 = fminf(mind2, d2);
    dst[(size_t)c * TT] = sqrtf(d2);
  }

  float v = mind2;
  #pragma unroll
  for (int off = 32; off; off >>= 1) v += __shfl_down(v, off, 64);
  if ((tid & 63) == 0) red[tid >> 6] = v;
  __syncthreads();
  if (tid == 0) atomicAdd(aux, red[0] + red[1] + red[2] + red[3]);
}

// ---------------- Kernel B: top-64 smallest per row, register-resident ----------------
// grid: (NC, H, 2B), block 256. Row (8192 dist values) in registers
// (u[32]/thread). Bitwise binary search for tau; same set semantics as the
// validated LDS version (rounds 4/5 produced byte-identical outputs with
// this machinery vs the LDS one). No LDS scans -> no 159us LDS-bound wall.
__global__ __launch_bounds__(256) void ktopk(
    const float* __restrict__ qd, const float* __restrict__ kd,
    int* __restrict__ idxq, int* __restrict__ idxk)
{
  __shared__ unsigned int red[4];
  __shared__ int outIdx[WW];
  __shared__ int tie[TIEMAX];
  __shared__ int pos, tpos;

  const int c = blockIdx.x, h = blockIdx.y;
  const int b = blockIdx.z >> 1, isK = blockIdx.z & 1;
  const int tid = threadIdx.x;
  const int lane = tid & 63, wid = tid >> 6;
  const size_t rowoff = ((size_t)(b * HH + h) * NCC + c) * TT;
  const float4* row4 = (const float4*)((isK ? kd : qd) + rowoff);

  unsigned int u[32];
  #pragma unroll
  for (int j = 0; j < 8; ++j) {
    float4 v = row4[j * 256 + tid];          // u[4j+m] is at index j*1024+tid*4+m
    u[4*j+0] = __float_as_uint(v.x);
    u[4*j+1] = __float_as_uint(v.y);
    u[4*j+2] = __float_as_uint(v.z);
    u[4*j+3] = __float_as_uint(v.w);
  }
  if (tid == 0) { pos = 0; tpos = 0; }

  unsigned int tau = 0u;
  for (int bit = 30; bit >= 0; --bit) {      // bit31 = sign, always 0 for dist
    const unsigned int cand = tau | (1u << bit);
    int cnt = 0;
    #pragma unroll
    for (int i = 0; i < 32; ++i) cnt += (u[i] < cand) ? 1 : 0;
    #pragma unroll
    for (int off = 32; off; off >>= 1) cnt += __shfl_down(cnt, off, 64);
    if (lane == 0) red[wid] = (unsigned int)cnt;
    __syncthreads();
    const int tot = (int)(red[0] + red[1] + red[2] + red[3]);
    if (tot < WW) tau = cand;                // 64th smallest >= cand
    __syncthreads();
  }
  // base = count(u < tau); need = 64 - base taken from u == tau (lowest idx)
  {
    int cnt = 0;
    #pragma unroll
    for (int i = 0; i < 32; ++i) cnt += (u[i] < tau) ? 1 : 0;
    #pragma unroll
    for (int off = 32; off; off >>= 1) cnt += __shfl_down(cnt, off, 64);
    if (lane == 0) red[wid] = (unsigned int)cnt;
  }
  __syncthreads();
  const int base = (int)(red[0] + red[1] + red[2] + red[3]);
  const int need = WW - base;

  #pragma unroll
  for (int i = 0; i < 32; ++i) {
    const int idx = (i >> 2) * 1024 + tid * 4 + (i & 3);
    if (u[i] < tau) {
      int p = atomicAdd(&pos, 1); outIdx[p] = idx;
    } else if (u[i] == tau) {
      int p = atomicAdd(&tpos, 1);
      if (p < TIEMAX) tie[p] = idx;          // >TIEMAX exact-equal values: pathological
    }
  }
  __syncthreads();
  const int tc = tpos < TIEMAX ? tpos : TIEMAX;
  if (tc == need) {
    if (tid < need) outIdx[base + tid] = tie[tid];   // all ties taken; order irrelevant
  } else if (tid == 0) {
    int last = -1;                            // rare: pick `need` lowest tie indices
    for (int e = 0; e < need; ++e) {
      int mn = 0x7fffffff;
      for (int s = 0; s < tc; ++s) { int t = tie[s]; if (t > last && t < mn) mn = t; }
      outIdx[base + e] = mn; last = mn;
    }
  }
  __syncthreads();
  int* dstp = (isK ? idxk : idxq) + ((size_t)(b * HH + h) * NCC + c) * WW;
  if (tid < WW) dstp[tid] = outIdx[tid];
}

// ---------------- Kernel C: gather + attention -> dense per-cluster out ----------------
// ROUND-6 VERBATIM. Do NOT replace the scalar acc[64] with a float4 array:
// the final store indexes acc with the per-lane `part` value, and a float4
// register array there demoted to scratch (round-7: 2.5 GB spill writes,
// 765us). Scalar form compiles to 4 constant-index arms and stays in VGPRs.
__global__ __launch_bounds__(256) void kattn(
    const float* __restrict__ q, const float* __restrict__ kg,
    const float* __restrict__ vg, const float* __restrict__ memk,
    const float* __restrict__ memv, const int* __restrict__ idxq,
    const int* __restrict__ idxk, float* __restrict__ outc)
{
  __shared__ float Ks[(MM + WW) * SK];   // 68 x 65 floats = 17.7 KB
  __shared__ float Vs[(MM + WW) * SK];
  __shared__ int tq[WW];
  __shared__ int tk[WW];

  const int c = blockIdx.x, h = blockIdx.y, b = blockIdx.z;
  const int tid = threadIdx.x;
  const size_t bh = (size_t)(b * HH + h);

  if (tid < WW) tq[tid] = idxq[(bh * NCC + c) * WW + tid];
  else if (tid < 2 * WW) tk[tid - WW] = idxk[(bh * NCC + c) * WW + tid - WW];
  __syncthreads();

  const int r = tid >> 2, part = tid & 3;

  for (int j = r; j < MM + WW; j += 64) {
    const float* sk = (j < MM)
        ? memk + (((size_t)(h * NCC + c)) * MM + j) * DD + part * 16
        : kg + (bh * TT + tk[j - MM]) * DD + part * 16;
    const float* sv = (j < MM)
        ? memv + (((size_t)(h * NCC + c)) * MM + j) * DD + part * 16
        : vg + (bh * TT + tk[j - MM]) * DD + part * 16;
    #pragma unroll
    for (int i = 0; i < 4; ++i) {
      *(float4*)&Ks[j * SK + part * 16 + 4 * i] = ((const float4*)sk)[i];
      *(float4*)&Vs[j * SK + part * 16 + 4 * i] = ((const float4*)sv)[i];
    }
  }
  __syncthreads();

  float s[17];
  {
    float qr[DD];
    const float* qsrc = q + (bh * TT + tq[r]) * DD;
    #pragma unroll
    for (int i = 0; i < DD / 4; ++i) {
      float4 v = ((const float4*)qsrc)[i];
      qr[4*i] = v.x; qr[4*i+1] = v.y; qr[4*i+2] = v.z; qr[4*i+3] = v.w;
    }
    #pragma unroll
    for (int jj = 0; jj < 17; ++jj) {
      const float* krow = &Ks[(part * 17 + jj) * SK];
      float acc = 0.f;
      #pragma unroll
      for (int d = 0; d < DD; ++d) acc += qr[d] * krow[d];
      s[jj] = acc * 0.125f;
    }
  }
  float mx = s[0];
  #pragma unroll
  for (int jj = 1; jj < 17; ++jj) mx = fmaxf(mx, s[jj]);
  mx = fmaxf(mx, __shfl_xor(mx, 1, 64));
  mx = fmaxf(mx, __shfl_xor(mx, 2, 64));
  float sum = 0.f;
  #pragma unroll
  for (int jj = 0; jj < 17; ++jj) { s[jj] = expf(s[jj] - mx); sum += s[jj]; }
  sum += __shfl_xor(sum, 1, 64);
  sum += __shfl_xor(sum, 2, 64);
  const float inv = 1.f / sum;
  #pragma unroll
  for (int jj = 0; jj < 17; ++jj) s[jj] *= inv;

  float acc[DD];
  #pragma unroll
  for (int d = 0; d < DD; ++d) acc[d] = 0.f;
  #pragma unroll
  for (int jj = 0; jj < 17; ++jj) {
    const float p = s[jj];
    const float* vrow = &Vs[(part * 17 + jj) * SK];
    #pragma unroll
    for (int d = 0; d < DD; ++d) acc[d] += p * vrow[d];
  }
  #pragma unroll
  for (int d = 0; d < DD; ++d) {
    acc[d] += __shfl_xor(acc[d], 1, 64);
    acc[d] += __shfl_xor(acc[d], 2, 64);
  }
  float* obase = outc + (((bh * NCC + c) * WW) + r) * DD + part * 16;
  #pragma unroll
  for (int i = 0; i < 4; ++i)
    ((float4*)obase)[i] = make_float4(acc[part*16+4*i], acc[part*16+4*i+1],
                                      acc[part*16+4*i+2], acc[part*16+4*i+3]);
}

// ---------------- Kernel C2: inverted index (one int atomic per selection) ----------------
__global__ __launch_bounds__(256) void kindex(
    const int* __restrict__ idxq, const float* __restrict__ outc,
    int* __restrict__ cnt, int* __restrict__ slots, float* __restrict__ out)
{
  const int i = blockIdx.x * 256 + threadIdx.x;       // over B*H*NC*W
  const int bh = i >> 13;                             // NC*W = 8192
  const int e = i & 8191;
  const int t = idxq[i];
  const int row = bh * TT + t;
  const int p = atomicAdd(&cnt[row], 1);
  if (p < SMAX) {
    slots[(size_t)row * SMAX + p] = e;
  } else {
    const float* src = outc + ((size_t)(bh * (NCC * WW)) + e) * DD;
    for (int d = 0; d < DD; ++d) atomicAdd(&out[(size_t)row * DD + d], src[d]);
  }
}

// ---------------- Kernel D: gather slots + divide + aux ----------------
__global__ __launch_bounds__(256) void kfinal(
    float* __restrict__ outp, const int* __restrict__ cnt,
    const int* __restrict__ slots, const float* __restrict__ outc,
    const float* __restrict__ aux)
{
  const size_t n = (size_t)BB * HH * TT * DD;
  const size_t i = (size_t)blockIdx.x * 256 + threadIdx.x;
  if (i < n) {
    const int row = (int)(i >> 6);
    const int d = (int)(i & 63);
    const int bh = row >> 13;
    const int c = cnt[row];
    const int m = c < SMAX ? c : SMAX;
    float sum = outp[i];
    for (int s = 0; s < m; ++s) {
      const int e = slots[(size_t)row * SMAX + s];
      sum += outc[((size_t)(bh * (NCC * WW)) + e) * DD + d];
    }
    outp[i] = sum / ((float)c + 1e-5f);
  }
  if (i == 0) outp[n] = aux[0] * (0.0001f / (float)((size_t)BB * HH * 2 * TT * DD));
}

extern "C" void kernel_launch(void* const* d_in, const int* in_sizes, int n_in,
                              void* d_out, int out_size, void* d_ws, size_t ws_size,
                              hipStream_t stream) {
  (void)in_sizes; (void)n_in; (void)out_size; (void)ws_size;
  const float* q     = (const float*)d_in[0];
  const float* k     = (const float*)d_in[1];
  const float* v     = (const float*)d_in[2];
  const float* means = (const float*)d_in[3];
  const float* memk  = (const float*)d_in[4];
  const float* memv  = (const float*)d_in[5];
  float* out = (float*)d_out;

  const size_t NQ   = (size_t)BB * HH * NCC * TT;   // 16,777,216
  const size_t NIDX = (size_t)BB * HH * NCC * WW;   // 131,072
  const size_t NROW = (size_t)BB * HH * TT;         // 131,072

  float* qd   = (float*)d_ws;
  float* kd   = qd + NQ;
  int*   idxq = (int*)(kd + NQ);
  int*   idxk = idxq + NIDX;
  int*   cnt  = idxk + NIDX;
  float* aux  = (float*)(cnt + NROW);
  float* outc  = qd;                                // dead after ktopk -> reuse
  int*   slots = (int*)kd;

  const size_t n = (size_t)BB * HH * TT * DD;
  hipMemsetAsync(out, 0, n * sizeof(float), stream);
  hipMemsetAsync(cnt, 0, (NROW + 1) * sizeof(int), stream);  // cnt + aux

  kdist<<<dim3(T2 / 256, HH, BB), 256, 0, stream>>>(q, k, means, qd, kd, aux);
  ktopk<<<dim3(NCC, HH, 2 * BB), 256, 0, stream>>>(qd, kd, idxq, idxk);
  kattn<<<dim3(NCC, HH, BB), 256, 0, stream>>>(q, k, v, memk, memv, idxq, idxk, outc);
  kindex<<<(int)(NIDX / 256), 256, 0, stream>>>(idxq, outc, cnt, slots, out);
  kfinal<<<(int)((n + 255) / 256), 256, 0, stream>>>(out, cnt, slots, outc, aux);
}

// Round 9
// 429.215 us; speedup vs baseline: 2.8929x; 1.1137x over previous
//
#include <hip/hip_runtime.h>
#include <math.h>

#define BB 2
#define TT 8192
#define HH 8
#define DD 64
#define NCC 128
#define MM 4
#define WW (TT/NCC)     // 64
#define T2 (2*TT)
#define CH 64           // clusters per kdist block (c-split x2)
#define SMAX 32         // slot cap per target row (cnt<=NC=128; overflow path below)
#define SK 68           // LDS row stride: 68*4=272 B, 16B-aligned -> ds_read_b128
#define TIEMAX 256

// ---------------- Kernel A: normalize + cdist + per-t' min via atomicMin ----------------
// Math body is ROUND-2 VERBATIM — FROZEN (rounds 3-5: any contraction change
// flips top-64 boundary picks). This round only splits the c-range across 2
// blocks (occupancy 16->32 waves/CU) and swaps the aux block-sum for a
// per-t' atomicMin (fminf over subsets is order-invariant -> bits identical).
__global__ __launch_bounds__(256) void kdist(
    const float* __restrict__ q, const float* __restrict__ k,
    const float* __restrict__ means,
    float* __restrict__ qd, float* __restrict__ kd,
    unsigned int* __restrict__ minb)
{
  __shared__ float sm[CH * DD];
  __shared__ float sm2[CH];
  const int b = blockIdx.z >> 1, h = blockIdx.y;
  const int c0 = (blockIdx.z & 1) * CH;
  const int tid = threadIdx.x;

  const float4* mp = (const float4*)(means + ((size_t)h * NCC + c0) * DD);
  float4* smp = (float4*)sm;
  for (int i = tid; i < CH * DD / 4; i += 256) smp[i] = mp[i];
  __syncthreads();
  if (tid < CH) {
    float s = 0.f;
    #pragma unroll
    for (int d = 0; d < DD; ++d) { float v = sm[tid * DD + d]; s += v * v; }
    sm2[tid] = s;
  }
  __syncthreads();

  const int tp = blockIdx.x * 256 + tid;               // t' in [0,2T)
  const size_t bh = (size_t)(b * HH + h);
  const float* src = (tp < TT) ? (q + (bh * TT + tp) * DD)
                               : (k + (bh * TT + (tp - TT)) * DD);
  float x[DD];
  float ss = 0.f;
  #pragma unroll
  for (int i = 0; i < DD / 4; ++i) {
    float4 v = ((const float4*)src)[i];
    x[4*i] = v.x; x[4*i+1] = v.y; x[4*i+2] = v.z; x[4*i+3] = v.w;
    ss += v.x*v.x + v.y*v.y + v.z*v.z + v.w*v.w;
  }
  const float scale = 1.f / (sqrtf(ss) + 1e-6f);
  float x2 = 0.f;
  #pragma unroll
  for (int i = 0; i < DD; ++i) { x[i] *= scale; x2 += x[i] * x[i]; }

  float* dst = (tp < TT) ? (qd + (bh * NCC) * TT + tp)
                         : (kd + (bh * NCC) * TT + (tp - TT));
  float mind2 = 1e30f;
  for (int c = 0; c < CH; ++c) {
    const float* mrow = sm + c * DD;
    float dot = 0.f;
    #pragma unroll
    for (int d = 0; d < DD; ++d) dot += x[d] * mrow[d];
    float d2 = fmaxf(x2 + sm2[c] - 2.f * dot, 0.f);
    mind2 = fminf(mind2, d2);
    dst[(size_t)(c0 + c) * TT] = sqrtf(d2);
  }

  atomicMin(&minb[bh * T2 + tp], __float_as_uint(mind2));   // d2>=0: bits monotone
}

// ---------------- Kernel A2: sum per-t' minima -> aux ----------------
__global__ __launch_bounds__(256) void kaux(
    const unsigned int* __restrict__ minb, float* __restrict__ aux)
{
  __shared__ float red[4];
  const int i = blockIdx.x * 256 + threadIdx.x;        // over BB*HH*T2
  float v = __uint_as_float(minb[i]);
  #pragma unroll
  for (int off = 32; off; off >>= 1) v += __shfl_down(v, off, 64);
  if ((threadIdx.x & 63) == 0) red[threadIdx.x >> 6] = v;
  __syncthreads();
  if (threadIdx.x == 0) atomicAdd(aux, red[0] + red[1] + red[2] + red[3]);
}

// ---------------- Kernel B: top-64 smallest per row, register-resident ----------------
// ROUND-8 VERBATIM (validated). Row in registers (u[32]/thread); bitwise
// binary search for tau; lowest-index ties match jax.lax.top_k.
__global__ __launch_bounds__(256) void ktopk(
    const float* __restrict__ qd, const float* __restrict__ kd,
    int* __restrict__ idxq, int* __restrict__ idxk)
{
  __shared__ unsigned int red[4];
  __shared__ int outIdx[WW];
  __shared__ int tie[TIEMAX];
  __shared__ int pos, tpos;

  const int c = blockIdx.x, h = blockIdx.y;
  const int b = blockIdx.z >> 1, isK = blockIdx.z & 1;
  const int tid = threadIdx.x;
  const int lane = tid & 63, wid = tid >> 6;
  const size_t rowoff = ((size_t)(b * HH + h) * NCC + c) * TT;
  const float4* row4 = (const float4*)((isK ? kd : qd) + rowoff);

  unsigned int u[32];
  #pragma unroll
  for (int j = 0; j < 8; ++j) {
    float4 v = row4[j * 256 + tid];          // u[4j+m] is at index j*1024+tid*4+m
    u[4*j+0] = __float_as_uint(v.x);
    u[4*j+1] = __float_as_uint(v.y);
    u[4*j+2] = __float_as_uint(v.z);
    u[4*j+3] = __float_as_uint(v.w);
  }
  if (tid == 0) { pos = 0; tpos = 0; }

  unsigned int tau = 0u;
  for (int bit = 30; bit >= 0; --bit) {      // bit31 = sign, always 0 for dist
    const unsigned int cand = tau | (1u << bit);
    int cnt = 0;
    #pragma unroll
    for (int i = 0; i < 32; ++i) cnt += (u[i] < cand) ? 1 : 0;
    #pragma unroll
    for (int off = 32; off; off >>= 1) cnt += __shfl_down(cnt, off, 64);
    if (lane == 0) red[wid] = (unsigned int)cnt;
    __syncthreads();
    const int tot = (int)(red[0] + red[1] + red[2] + red[3]);
    if (tot < WW) tau = cand;                // 64th smallest >= cand
    __syncthreads();
  }
  {
    int cnt = 0;
    #pragma unroll
    for (int i = 0; i < 32; ++i) cnt += (u[i] < tau) ? 1 : 0;
    #pragma unroll
    for (int off = 32; off; off >>= 1) cnt += __shfl_down(cnt, off, 64);
    if (lane == 0) red[wid] = (unsigned int)cnt;
  }
  __syncthreads();
  const int base = (int)(red[0] + red[1] + red[2] + red[3]);
  const int need = WW - base;

  #pragma unroll
  for (int i = 0; i < 32; ++i) {
    const int idx = (i >> 2) * 1024 + tid * 4 + (i & 3);
    if (u[i] < tau) {
      int p = atomicAdd(&pos, 1); outIdx[p] = idx;
    } else if (u[i] == tau) {
      int p = atomicAdd(&tpos, 1);
      if (p < TIEMAX) tie[p] = idx;          // >TIEMAX exact-equal values: pathological
    }
  }
  __syncthreads();
  const int tc = tpos < TIEMAX ? tpos : TIEMAX;
  if (tc == need) {
    if (tid < need) outIdx[base + tid] = tie[tid];   // all ties taken; order irrelevant
  } else if (tid == 0) {
    int last = -1;                            // rare: pick `need` lowest tie indices
    for (int e = 0; e < need; ++e) {
      int mn = 0x7fffffff;
      for (int s = 0; s < tc; ++s) { int t = tie[s]; if (t > last && t < mn) mn = t; }
      outIdx[base + e] = mn; last = mn;
    }
  }
  __syncthreads();
  int* dstp = (isK ? idxk : idxq) + ((size_t)(b * HH + h) * NCC + c) * WW;
  if (tid < WW) dstp[tid] = outIdx[tid];
}

// ---------------- Kernel C: gather + attention -> dense per-cluster out ----------------
// grid: (NC, H, B), block 256. SK=68 -> b128 LDS reads. P round-trips through
// LDS (reusing Ks after QK^T), so PV accumulators are CONSTANT-indexed float4
// (round-7 lesson: any per-lane-variable index into a register array demotes
// it to scratch -> GBs of spill traffic). No atomics; coalesced stores.
__global__ __launch_bounds__(256) void kattn(
    const float* __restrict__ q, const float* __restrict__ kg,
    const float* __restrict__ vg, const float* __restrict__ memk,
    const float* __restrict__ memv, const int* __restrict__ idxq,
    const int* __restrict__ idxk, float* __restrict__ outc)
{
  __shared__ float Ks[(MM + WW) * SK];   // 68 x 68 floats = 18.5 KB; becomes Ps
  __shared__ float Vs[(MM + WW) * SK];
  __shared__ int tq[WW];
  __shared__ int tk[WW];

  const int c = blockIdx.x, h = blockIdx.y, b = blockIdx.z;
  const int tid = threadIdx.x;
  const size_t bh = (size_t)(b * HH + h);

  if (tid < WW) tq[tid] = idxq[(bh * NCC + c) * WW + tid];
  else if (tid < 2 * WW) tk[tid - WW] = idxk[(bh * NCC + c) * WW + tid - WW];
  __syncthreads();

  const int r = tid >> 2, part = tid & 3;

  for (int j = r; j < MM + WW; j += 64) {
    const float* sk = (j < MM)
        ? memk + (((size_t)(h * NCC + c)) * MM + j) * DD + part * 16
        : kg + (bh * TT + tk[j - MM]) * DD + part * 16;
    const float* sv = (j < MM)
        ? memv + (((size_t)(h * NCC + c)) * MM + j) * DD + part * 16
        : vg + (bh * TT + tk[j - MM]) * DD + part * 16;
    #pragma unroll
    for (int i = 0; i < 4; ++i) {
      *(float4*)&Ks[j * SK + part * 16 + 4 * i] = ((const float4*)sk)[i];
      *(float4*)&Vs[j * SK + part * 16 + 4 * i] = ((const float4*)sv)[i];
    }
  }
  __syncthreads();

  // QK^T: thread (r, part) handles keys j = part*17 + jj
  float s[17];
  {
    float qr[DD];
    const float* qsrc = q + (bh * TT + tq[r]) * DD;
    #pragma unroll
    for (int i = 0; i < DD / 4; ++i) {
      float4 v = ((const float4*)qsrc)[i];
      qr[4*i] = v.x; qr[4*i+1] = v.y; qr[4*i+2] = v.z; qr[4*i+3] = v.w;
    }
    #pragma unroll
    for (int jj = 0; jj < 17; ++jj) {
      const float4* krow = (const float4*)&Ks[(part * 17 + jj) * SK];
      float a0 = 0.f, a1 = 0.f, a2 = 0.f, a3 = 0.f;
      #pragma unroll
      for (int i = 0; i < DD / 4; ++i) {
        float4 kv = krow[i];
        a0 = fmaf(qr[4*i+0], kv.x, a0);
        a1 = fmaf(qr[4*i+1], kv.y, a1);
        a2 = fmaf(qr[4*i+2], kv.z, a2);
        a3 = fmaf(qr[4*i+3], kv.w, a3);
      }
      s[jj] = ((a0 + a1) + (a2 + a3)) * 0.125f;
    }
  }
  // softmax across the quad (4 lanes = one query row)
  float mx = s[0];
  #pragma unroll
  for (int jj = 1; jj < 17; ++jj) mx = fmaxf(mx, s[jj]);
  mx = fmaxf(mx, __shfl_xor(mx, 1, 64));
  mx = fmaxf(mx, __shfl_xor(mx, 2, 64));
  float sum = 0.f;
  #pragma unroll
  for (int jj = 0; jj < 17; ++jj) { s[jj] = expf(s[jj] - mx); sum += s[jj]; }
  sum += __shfl_xor(sum, 1, 64);
  sum += __shfl_xor(sum, 2, 64);
  const float inv = 1.f / sum;
  #pragma unroll
  for (int jj = 0; jj < 17; ++jj) s[jj] *= inv;

  __syncthreads();                       // all QK reads of Ks complete
  #pragma unroll
  for (int jj = 0; jj < 17; ++jj) Ks[r * SK + part * 17 + jj] = s[jj];
  __syncthreads();                       // Ps ready

  // PV: thread (r, part) owns out[r][part*16 .. part*16+16) — constant-index accs
  float4 a0 = make_float4(0.f,0.f,0.f,0.f), a1 = a0, a2 = a0, a3 = a0;
  for (int j = 0; j < MM + WW; ++j) {
    const float p = Ks[r * SK + j];
    const float4* vrow = (const float4*)&Vs[j * SK + part * 16];
    float4 v0 = vrow[0], v1 = vrow[1], v2 = vrow[2], v3 = vrow[3];
    a0.x = fmaf(p, v0.x, a0.x); a0.y = fmaf(p, v0.y, a0.y);
    a0.z = fmaf(p, v0.z, a0.z); a0.w = fmaf(p, v0.w, a0.w);
    a1.x = fmaf(p, v1.x, a1.x); a1.y = fmaf(p, v1.y, a1.y);
    a1.z = fmaf(p, v1.z, a1.z); a1.w = fmaf(p, v1.w, a1.w);
    a2.x = fmaf(p, v2.x, a2.x); a2.y = fmaf(p, v2.y, a2.y);
    a2.z = fmaf(p, v2.z, a2.z); a2.w = fmaf(p, v2.w, a2.w);
    a3.x = fmaf(p, v3.x, a3.x); a3.y = fmaf(p, v3.y, a3.y);
    a3.z = fmaf(p, v3.z, a3.z); a3.w = fmaf(p, v3.w, a3.w);
  }
  float4* obase = (float4*)(outc + (((bh * NCC + c) * WW) + r) * DD + part * 16);
  obase[0] = a0; obase[1] = a1; obase[2] = a2; obase[3] = a3;
}

// ---------------- Kernel C2: inverted index (one int atomic per selection) ----------------
__global__ __launch_bounds__(256) void kindex(
    const int* __restrict__ idxq, const float* __restrict__ outc,
    int* __restrict__ cnt, int* __restrict__ slots, float* __restrict__ out)
{
  const int i = blockIdx.x * 256 + threadIdx.x;       // over B*H*NC*W
  const int bh = i >> 13;                             // NC*W = 8192
  const int e = i & 8191;
  const int t = idxq[i];
  const int row = bh * TT + t;
  const int p = atomicAdd(&cnt[row], 1);
  if (p < SMAX) {
    slots[(size_t)row * SMAX + p] = e;
  } else {
    const float* src = outc + ((size_t)(bh * (NCC * WW)) + e) * DD;
    for (int d = 0; d < DD; ++d) atomicAdd(&out[(size_t)row * DD + d], src[d]);
  }
}

// ---------------- Kernel D: gather slots + divide + aux ----------------
__global__ __launch_bounds__(256) void kfinal(
    float* __restrict__ outp, const int* __restrict__ cnt,
    const int* __restrict__ slots, const float* __restrict__ outc,
    const float* __restrict__ aux)
{
  const size_t n = (size_t)BB * HH * TT * DD;
  const size_t i = (size_t)blockIdx.x * 256 + threadIdx.x;
  if (i < n) {
    const int row = (int)(i >> 6);
    const int d = (int)(i & 63);
    const int bh = row >> 13;
    const int c = cnt[row];
    const int m = c < SMAX ? c : SMAX;
    float sum = outp[i];
    for (int s = 0; s < m; ++s) {
      const int e = slots[(size_t)row * SMAX + s];
      sum += outc[((size_t)(bh * (NCC * WW)) + e) * DD + d];
    }
    outp[i] = sum / ((float)c + 1e-5f);
  }
  if (i == 0) outp[n] = aux[0] * (0.0001f / (float)((size_t)BB * HH * 2 * TT * DD));
}

extern "C" void kernel_launch(void* const* d_in, const int* in_sizes, int n_in,
                              void* d_out, int out_size, void* d_ws, size_t ws_size,
                              hipStream_t stream) {
  (void)in_sizes; (void)n_in; (void)out_size; (void)ws_size;
  const float* q     = (const float*)d_in[0];
  const float* k     = (const float*)d_in[1];
  const float* v     = (const float*)d_in[2];
  const float* means = (const float*)d_in[3];
  const float* memk  = (const float*)d_in[4];
  const float* memv  = (const float*)d_in[5];
  float* out = (float*)d_out;

  const size_t NQ   = (size_t)BB * HH * NCC * TT;   // 16,777,216
  const size_t NIDX = (size_t)BB * HH * NCC * WW;   // 131,072
  const size_t NROW = (size_t)BB * HH * TT;         // 131,072
  const size_t NMIN = (size_t)BB * HH * T2;         // 262,144

  float*        qd   = (float*)d_ws;
  float*        kd   = qd + NQ;
  int*          idxq = (int*)(kd + NQ);
  int*          idxk = idxq + NIDX;
  int*          cnt  = idxk + NIDX;
  float*        aux  = (float*)(cnt + NROW);
  unsigned int* minb = (unsigned int*)(aux + 1);
  float*        outc  = qd;                         // dead after ktopk -> reuse
  int*          slots = (int*)kd;

  const size_t n = (size_t)BB * HH * TT * DD;
  hipMemsetAsync(out, 0, n * sizeof(float), stream);
  hipMemsetAsync(cnt, 0, (NROW + 1) * sizeof(int), stream);   // cnt + aux
  hipMemsetAsync(minb, 0x7f, NMIN * sizeof(unsigned int), stream);  // +inf-ish floats

  kdist<<<dim3(T2 / 256, HH, BB * 2), 256, 0, stream>>>(q, k, means, qd, kd, minb);
  kaux<<<(int)(NMIN / 256), 256, 0, stream>>>(minb, aux);
  ktopk<<<dim3(NCC, HH, 2 * BB), 256, 0, stream>>>(qd, kd, idxq, idxk);
  kattn<<<dim3(NCC, HH, BB), 256, 0, stream>>>(q, k, v, memk, memv, idxq, idxk, outc);
  kindex<<<(int)(NIDX / 256), 256, 0, stream>>>(idxq, outc, cnt, slots, out);
  kfinal<<<(int)((n + 255) / 256), 256, 0, stream>>>(out, cnt, slots, outc, aux);
}